// Round 9
// baseline (341.335 us; speedup 1.0000x reference)
//
#include <hip/hip_runtime.h>
#include <math.h>

#define Bb 8
#define Nn 2048
#define ALPHA 0.2f
#define LN_EPS 1e-5f
#define LOG2E 1.4426950408889634f

typedef __attribute__((ext_vector_type(8))) short short8;
typedef __attribute__((ext_vector_type(4))) float f32x4;
typedef __attribute__((ext_vector_type(4))) int int4v;

__device__ inline unsigned short f2bf(float f) {
    unsigned u = __builtin_bit_cast(unsigned, f);
    u += 0x7fffu + ((u >> 16) & 1u);   // RNE
    return (unsigned short)(u >> 16);
}

__device__ __forceinline__ void gll16(const void* g, void* l) {
    __builtin_amdgcn_global_load_lds(
        (const __attribute__((address_space(1))) unsigned int*)g,
        (__attribute__((address_space(3))) unsigned int*)l, 16, 0, 0);
}

__device__ __forceinline__ void sink8(short8 v) {   // keep value live, 0 instrs
    int4v u = __builtin_bit_cast(int4v, v);
    asm volatile("" :: "v"(u.x), "v"(u.y), "v"(u.z), "v"(u.w));
}

// ------ Kernel A: pack adj into TRANSPOSED bitmask bitsT[i>>4][w][i&15] ------
__global__ __launch_bounds__(256) void pack_mask(const int* __restrict__ adj,
                                                 unsigned int* __restrict__ bitsT) {
    int g = blockIdx.x * blockDim.x + threadIdx.x;
    int lane = threadIdx.x & 63;
    int pred = adj[g] > 0;
    unsigned long long b = __ballot(pred);
    if ((lane & 31) == 0) {
        unsigned w32 = (unsigned)(b >> (lane & 32));
        int i = g >> 11, w = (g >> 5) & 63;
        bitsT[((size_t)(i >> 4) * 64 + w) * 16 + (i & 15)] = w32;
    }
}

// -- Kernel B: x-scale, h=x@W, LayerNorm, s1L/s2L (pre-scaled by log2e), hT2 --
__global__ __launch_bounds__(256) void node_transform(
    const float* __restrict__ in, const float* __restrict__ W,
    const float* __restrict__ a, const float* __restrict__ nw,
    const float* __restrict__ nb, const float* __restrict__ gam,
    const float* __restrict__ bet,
    float* __restrict__ h, float* __restrict__ s1L, float* __restrict__ s2L,
    unsigned short* __restrict__ hT2)
{
    __shared__ float Wl[64 * 64];
    __shared__ unsigned short h_bf[4][64];
    int t = threadIdx.x;
#pragma unroll
    for (int s = 0; s < 4; ++s)
        ((float4*)Wl)[t + 256 * s] = ((const float4*)W)[t + 256 * s];
    __syncthreads();
    int wv = t >> 6, lane = t & 63;
    int node = blockIdx.x * 4 + wv;
    int n = node & (Nn - 1);
    float xv = in[node * 64 + lane] * (nw[n] + 1.0f) + nb[n];
    float hv0 = 0.f, hv1 = 0.f, hv2 = 0.f, hv3 = 0.f;
#pragma unroll
    for (int k4 = 0; k4 < 16; ++k4) {
        hv0 = fmaf(__shfl(xv, k4 * 4 + 0, 64), Wl[(k4 * 4 + 0) * 64 + lane], hv0);
        hv1 = fmaf(__shfl(xv, k4 * 4 + 1, 64), Wl[(k4 * 4 + 1) * 64 + lane], hv1);
        hv2 = fmaf(__shfl(xv, k4 * 4 + 2, 64), Wl[(k4 * 4 + 2) * 64 + lane], hv2);
        hv3 = fmaf(__shfl(xv, k4 * 4 + 3, 64), Wl[(k4 * 4 + 3) * 64 + lane], hv3);
    }
    float hv = (hv0 + hv1) + (hv2 + hv3);
    float mu = hv;
#pragma unroll
    for (int o = 32; o; o >>= 1) mu += __shfl_xor(mu, o, 64);
    mu *= (1.f / 64.f);
    float d = hv - mu;
    float var = d * d;
#pragma unroll
    for (int o = 32; o; o >>= 1) var += __shfl_xor(var, o, 64);
    var *= (1.f / 64.f);
    float hn = d * rsqrtf(var + LN_EPS) * gam[lane] + bet[lane];
    h[node * 64 + lane] = hn;
    h_bf[wv][lane] = f2bf(hn);
    float p1 = hn * a[lane], p2 = hn * a[64 + lane];
#pragma unroll
    for (int o = 32; o; o >>= 1) {
        p1 += __shfl_xor(p1, o, 64);
        p2 += __shfl_xor(p2, o, 64);
    }
    if (lane == 0) { s1L[node] = p1 * LOG2E; s2L[node] = p2 * LOG2E; }
    __syncthreads();
    if (t < 64) {
        int fb = t >> 4, am2 = t & 15;
        int node0 = blockIdx.x * 4;
        int b = node0 >> 11, j0 = node0 & (Nn - 1);
        int jw = j0 >> 5, ag2 = (j0 & 31) >> 3, e0 = j0 & 7;
        unsigned short v[4];
#pragma unroll
        for (int i = 0; i < 4; ++i) v[i] = h_bf[i][fb * 16 + am2];
        size_t dst = ((size_t)((b * 64 + jw) * 4 + fb)) * 512 + (ag2 * 16 + am2) * 8 + e0;
        *(uint2*)&hT2[dst] = *(uint2*)v;
    }
}

// ---- ABLATION PROBE: r8's attention7, phases peeled by template V ----------
// V=0 full | V=1 -MFMA | V=2 -MFMA -fragread -staging (keep barriers)
// V=3 pure P-gen (no barriers) | V=4 full but stage loop NOT unrolled
template <int V, int REP>
__global__ __launch_bounds__(256) void attn_probe(
    const float* __restrict__ h, const unsigned short* __restrict__ hT2,
    const float* __restrict__ s1L, const float* __restrict__ s2L,
    const unsigned int* __restrict__ bitsT, float* __restrict__ dst)
{
    __shared__ __align__(16) unsigned short frag[2][8][4][512];  // 64 KB
    __shared__ __align__(16) unsigned int mask_lds[2][64][16];   // 8 KB
    __shared__ __align__(16) float s2l[2048];                    // 8 KB

    int t = threadIdx.x, wv = t >> 6, lane = t & 63;
    int am = lane & 15, ag = lane >> 4;
    int rr = wv & 1, js = wv >> 1;
    int bx = blockIdx.x, b = blockIdx.y;

    float s1r = s1L[b * Nn + bx * 32 + rr * 16 + am];
    const unsigned int* msrc = bitsT + (size_t)(bx * 2) * 1024;
    const float* ssrc = s2L + b * Nn;
    const unsigned short* slab = hT2 + (size_t)b * 131072;

    // mask + s2 staging (once, all variants)
#pragma unroll
    for (int k = 0; k < 2; ++k) {
        int sl = wv * 2 + k;
        gll16(msrc + sl * 256 + lane * 4, &((unsigned int*)mask_lds)[sl * 256]);
        gll16(ssrc + sl * 256 + lane * 4, &s2l[sl * 256]);
    }
    asm volatile("s_waitcnt vmcnt(0)" ::: "memory");
    __builtin_amdgcn_s_barrier();

    const short8 vone = {(short)0x3F80, (short)0x3F80, (short)0x3F80, (short)0x3F80,
                         (short)0x3F80, (short)0x3F80, (short)0x3F80, (short)0x3F80};

    for (int rep = 0; rep < REP; ++rep) {
        __syncthreads();     // epilogue scratch (frag[0]) safe to overwrite

        f32x4 acc0 = {0,0,0,0}, acc1 = {0,0,0,0}, acc2 = {0,0,0,0}, acc3 = {0,0,0,0};
        f32x4 accz = {0,0,0,0};

        if constexpr (V == 0 || V == 1 || V == 4) {   // stage-0 frags
#pragma unroll
            for (int k = 0; k < 8; ++k) {
                int si = wv * 8 + k, w = si >> 2, fb = si & 3;
                gll16(slab + (size_t)(w * 4 + fb) * 512 + lane * 8, &frag[0][w][fb][0]);
            }
            asm volatile("s_waitcnt vmcnt(0)" ::: "memory");
            __builtin_amdgcn_s_barrier();
        }

        auto pstep = [&](int s, int wl) {
            int Wg = s * 8 + wl;
            unsigned wd = mask_lds[rr][Wg][am];
            float4 sa = *(const float4*)&s2l[Wg * 32 + 8 * ag];
            float4 sb = *(const float4*)&s2l[Wg * 32 + 8 * ag + 4];
            float se[8] = {sa.x, sa.y, sa.z, sa.w, sb.x, sb.y, sb.z, sb.w};
            float p[8];
#pragma unroll
            for (int e = 0; e < 8; ++e) {
                float x = s1r + se[e];
                float lr = fmaxf(x, ALPHA * x);
                float ev = __builtin_amdgcn_exp2f(lr);
                p[e] = ((wd >> (8 * ag + e)) & 1u) ? ev : 0.f;
            }
            int4v aw;
            aw.x = __builtin_amdgcn_perm(__builtin_bit_cast(unsigned, p[1]),
                                         __builtin_bit_cast(unsigned, p[0]), 0x07060302u);
            aw.y = __builtin_amdgcn_perm(__builtin_bit_cast(unsigned, p[3]),
                                         __builtin_bit_cast(unsigned, p[2]), 0x07060302u);
            aw.z = __builtin_amdgcn_perm(__builtin_bit_cast(unsigned, p[5]),
                                         __builtin_bit_cast(unsigned, p[4]), 0x07060302u);
            aw.w = __builtin_amdgcn_perm(__builtin_bit_cast(unsigned, p[7]),
                                         __builtin_bit_cast(unsigned, p[6]), 0x07060302u);
            short8 af = __builtin_bit_cast(short8, aw);
            if constexpr (V == 0 || V == 4) {
                short8 f0 = *(const short8*)&frag[s & 1][wl][0][lane * 8];
                short8 f1 = *(const short8*)&frag[s & 1][wl][1][lane * 8];
                short8 f2 = *(const short8*)&frag[s & 1][wl][2][lane * 8];
                short8 f3 = *(const short8*)&frag[s & 1][wl][3][lane * 8];
                acc0 = __builtin_amdgcn_mfma_f32_16x16x32_bf16(af, f0, acc0, 0, 0, 0);
                acc1 = __builtin_amdgcn_mfma_f32_16x16x32_bf16(af, f1, acc1, 0, 0, 0);
                acc2 = __builtin_amdgcn_mfma_f32_16x16x32_bf16(af, f2, acc2, 0, 0, 0);
                acc3 = __builtin_amdgcn_mfma_f32_16x16x32_bf16(af, f3, acc3, 0, 0, 0);
                accz = __builtin_amdgcn_mfma_f32_16x16x32_bf16(af, vone, accz, 0, 0, 0);
            } else if constexpr (V == 1) {
                short8 f0 = *(const short8*)&frag[s & 1][wl][0][lane * 8];
                short8 f1 = *(const short8*)&frag[s & 1][wl][1][lane * 8];
                short8 f2 = *(const short8*)&frag[s & 1][wl][2][lane * 8];
                short8 f3 = *(const short8*)&frag[s & 1][wl][3][lane * 8];
                sink8(af); sink8(f0); sink8(f1); sink8(f2); sink8(f3);
            } else {
                sink8(af);
            }
        };

        auto stage = [&](int s) {
            if constexpr (V == 0 || V == 1 || V == 4) {
                if (s < 7) {
#pragma unroll
                    for (int k = 0; k < 8; ++k) {
                        int si = wv * 8 + k, w = si >> 2, fb = si & 3;
                        gll16(slab + (size_t)(((s + 1) * 8 + w) * 4 + fb) * 512 + lane * 8,
                              &frag[(s + 1) & 1][w][fb][0]);
                    }
                }
            }
#pragma unroll
            for (int wi = 0; wi < 4; ++wi) pstep(s, js * 4 + wi);
            if constexpr (V == 0 || V == 1 || V == 4)
                asm volatile("s_waitcnt vmcnt(0)" ::: "memory");
            if constexpr (V != 3)
                __builtin_amdgcn_s_barrier();
        };

        if constexpr (V == 4) {
#pragma unroll 1
            for (int s = 0; s < 8; ++s) stage(s);
        } else {
#pragma unroll
            for (int s = 0; s < 8; ++s) stage(s);
        }

        // epilogue (identical all variants): combine j-halves, norm, resid, elu
        float* ep  = (float*)&frag[0][0][0][0];      // 16 KB scratch
        float* zep = (float*)&frag[0][4][0][0];      // next 256 B
#pragma unroll
        for (int q = 0; q < 4; ++q) {
            int rloc = rr * 16 + 4 * ag + q;
            ep[(js * 32 + rloc) * 64 +  0 + am] = acc0[q];
            ep[(js * 32 + rloc) * 64 + 16 + am] = acc1[q];
            ep[(js * 32 + rloc) * 64 + 32 + am] = acc2[q];
            ep[(js * 32 + rloc) * 64 + 48 + am] = acc3[q];
            if (am == 0) zep[js * 32 + rloc] = accz[q];
        }
        __syncthreads();

        int rl = t >> 3, fo = (t & 7) * 8;
        float zd = zep[rl] + zep[32 + rl];
        float zinv = 1.f / (zd != 0.f ? zd : 1.f);   // probes may have z=0
        size_t base = ((size_t)(b * Nn + bx * 32 + rl)) * 64 + fo;
        const float* e0p = &ep[rl * 64 + fo];
        const float* e1p = &ep[(32 + rl) * 64 + fo];
        float4 h0 = *(const float4*)&h[base];
        float4 h1 = *(const float4*)&h[base + 4];
        float4 o0, o1;
        o0.x = (e0p[0] + e1p[0]) * zinv + h0.x; o0.x = o0.x > 0.f ? o0.x : expm1f(o0.x);
        o0.y = (e0p[1] + e1p[1]) * zinv + h0.y; o0.y = o0.y > 0.f ? o0.y : expm1f(o0.y);
        o0.z = (e0p[2] + e1p[2]) * zinv + h0.z; o0.z = o0.z > 0.f ? o0.z : expm1f(o0.z);
        o0.w = (e0p[3] + e1p[3]) * zinv + h0.w; o0.w = o0.w > 0.f ? o0.w : expm1f(o0.w);
        o1.x = (e0p[4] + e1p[4]) * zinv + h1.x; o1.x = o1.x > 0.f ? o1.x : expm1f(o1.x);
        o1.y = (e0p[5] + e1p[5]) * zinv + h1.y; o1.y = o1.y > 0.f ? o1.y : expm1f(o1.y);
        o1.z = (e0p[6] + e1p[6]) * zinv + h1.z; o1.z = o1.z > 0.f ? o1.z : expm1f(o1.z);
        o1.w = (e0p[7] + e1p[7]) * zinv + h1.w; o1.w = o1.w > 0.f ? o1.w : expm1f(o1.w);
        *(float4*)&dst[base] = o0;
        *(float4*)&dst[base + 4] = o1;
    }
}

// ---------------- launch ----------------
extern "C" void kernel_launch(void* const* d_in, const int* in_sizes, int n_in,
                              void* d_out, int out_size, void* d_ws, size_t ws_size,
                              hipStream_t stream) {
    const float* in  = (const float*)d_in[0];
    const int*   adj = (const int*)d_in[1];
    const float* W   = (const float*)d_in[2];
    const float* a   = (const float*)d_in[3];
    const float* nw  = (const float*)d_in[4];
    const float* nb  = (const float*)d_in[5];
    const float* gam = (const float*)d_in[6];
    const float* bet = (const float*)d_in[7];
    float* out = (float*)d_out;

    char* ws = (char*)d_ws;
    float* h   = (float*)ws;                                       // 4 MB
    float* s1L = (float*)(ws + (size_t)Bb * Nn * 64 * 4);          // 64 KB
    float* s2L = s1L + (size_t)Bb * Nn;                            // 64 KB
    unsigned int* bitsT = (unsigned int*)(s2L + (size_t)Bb * Nn);  // 512 KB
    unsigned short* hT2 = (unsigned short*)(bitsT + (size_t)Nn * Nn / 32); // 2 MB
    float* pdump = (float*)(hT2 + (size_t)Bb * 64 * Nn);           // probe sinks
    size_t psz = (size_t)Bb * Nn * 64;                             // 4 MB each

    hipLaunchKernelGGL(pack_mask, dim3(Nn * Nn / 256), dim3(256), 0, stream, adj, bitsT);
    hipLaunchKernelGGL(node_transform, dim3(Bb * Nn / 4), dim3(256), 0, stream,
                       in, W, a, nw, nb, gam, bet, h, s1L, s2L, hT2);

    dim3 ag(Nn / 32, Bb), ab(256);
    hipLaunchKernelGGL((attn_probe<3, 4>), ag, ab, 0, stream, h, hT2, s1L, s2L, bitsT, pdump + 0 * psz);
    hipLaunchKernelGGL((attn_probe<2, 4>), ag, ab, 0, stream, h, hT2, s1L, s2L, bitsT, pdump + 1 * psz);
    hipLaunchKernelGGL((attn_probe<1, 4>), ag, ab, 0, stream, h, hT2, s1L, s2L, bitsT, pdump + 2 * psz);
    hipLaunchKernelGGL((attn_probe<4, 4>), ag, ab, 0, stream, h, hT2, s1L, s2L, bitsT, pdump + 3 * psz);
    hipLaunchKernelGGL((attn_probe<0, 4>), ag, ab, 0, stream, h, hT2, s1L, s2L, bitsT, out);
}

// Round 11
// 54.490 us; speedup vs baseline: 6.2641x; 6.2641x over previous
//
#include <hip/hip_runtime.h>
#include <math.h>

#define Bb 8
#define Nn 2048
#define ALPHA 0.2f
#define LN_EPS 1e-5f
#define LOG2E 1.4426950408889634f

typedef __attribute__((ext_vector_type(8))) short short8;
typedef __attribute__((ext_vector_type(4))) float f32x4;
typedef __attribute__((ext_vector_type(4))) int int4v;

__device__ inline unsigned short f2bf(float f) {
    unsigned u = __builtin_bit_cast(unsigned, f);
    u += 0x7fffu + ((u >> 16) & 1u);   // RNE
    return (unsigned short)(u >> 16);
}

__device__ __forceinline__ void gll16(const void* g, void* l) {
    __builtin_amdgcn_global_load_lds(
        (const __attribute__((address_space(1))) unsigned int*)g,
        (__attribute__((address_space(3))) unsigned int*)l, 16, 0, 0);
}

// ------ Kernel A: pack adj into TRANSPOSED bitmask bitsT[i>>4][w][i&15] ------
__global__ __launch_bounds__(256) void pack_mask(const int* __restrict__ adj,
                                                 unsigned int* __restrict__ bitsT) {
    int g = blockIdx.x * blockDim.x + threadIdx.x;
    int lane = threadIdx.x & 63;
    int pred = adj[g] > 0;
    unsigned long long b = __ballot(pred);
    if ((lane & 31) == 0) {
        unsigned w32 = (unsigned)(b >> (lane & 32));
        int i = g >> 11, w = (g >> 5) & 63;
        bitsT[((size_t)(i >> 4) * 64 + w) * 16 + (i & 15)] = w32;
    }
}

// -- Kernel B: x-scale, h=x@W, LayerNorm, s1L/s2L (pre-scaled by log2e), hT2 --
__global__ __launch_bounds__(256) void node_transform(
    const float* __restrict__ in, const float* __restrict__ W,
    const float* __restrict__ a, const float* __restrict__ nw,
    const float* __restrict__ nb, const float* __restrict__ gam,
    const float* __restrict__ bet,
    float* __restrict__ h, float* __restrict__ s1L, float* __restrict__ s2L,
    unsigned short* __restrict__ hT2)
{
    __shared__ float Wl[64 * 64];
    __shared__ unsigned short h_bf[4][64];
    int t = threadIdx.x;
#pragma unroll
    for (int s = 0; s < 4; ++s)
        ((float4*)Wl)[t + 256 * s] = ((const float4*)W)[t + 256 * s];
    __syncthreads();
    int wv = t >> 6, lane = t & 63;
    int node = blockIdx.x * 4 + wv;
    int n = node & (Nn - 1);
    float xv = in[node * 64 + lane] * (nw[n] + 1.0f) + nb[n];
    float hv0 = 0.f, hv1 = 0.f, hv2 = 0.f, hv3 = 0.f;
#pragma unroll
    for (int k4 = 0; k4 < 16; ++k4) {
        hv0 = fmaf(__shfl(xv, k4 * 4 + 0, 64), Wl[(k4 * 4 + 0) * 64 + lane], hv0);
        hv1 = fmaf(__shfl(xv, k4 * 4 + 1, 64), Wl[(k4 * 4 + 1) * 64 + lane], hv1);
        hv2 = fmaf(__shfl(xv, k4 * 4 + 2, 64), Wl[(k4 * 4 + 2) * 64 + lane], hv2);
        hv3 = fmaf(__shfl(xv, k4 * 4 + 3, 64), Wl[(k4 * 4 + 3) * 64 + lane], hv3);
    }
    float hv = (hv0 + hv1) + (hv2 + hv3);
    float mu = hv;
#pragma unroll
    for (int o = 32; o; o >>= 1) mu += __shfl_xor(mu, o, 64);
    mu *= (1.f / 64.f);
    float d = hv - mu;
    float var = d * d;
#pragma unroll
    for (int o = 32; o; o >>= 1) var += __shfl_xor(var, o, 64);
    var *= (1.f / 64.f);
    float hn = d * rsqrtf(var + LN_EPS) * gam[lane] + bet[lane];
    h[node * 64 + lane] = hn;
    h_bf[wv][lane] = f2bf(hn);
    float p1 = hn * a[lane], p2 = hn * a[64 + lane];
#pragma unroll
    for (int o = 32; o; o >>= 1) {
        p1 += __shfl_xor(p1, o, 64);
        p2 += __shfl_xor(p2, o, 64);
    }
    if (lane == 0) { s1L[node] = p1 * LOG2E; s2L[node] = p2 * LOG2E; }
    __syncthreads();
    if (t < 64) {
        int fb = t >> 4, am2 = t & 15;
        int node0 = blockIdx.x * 4;
        int b = node0 >> 11, j0 = node0 & (Nn - 1);
        int jw = j0 >> 5, ag2 = (j0 & 31) >> 3, e0 = j0 & 7;
        unsigned short v[4];
#pragma unroll
        for (int i = 0; i < 4; ++i) v[i] = h_bf[i][fb * 16 + am2];
        size_t dst = ((size_t)((b * 64 + jw) * 4 + fb)) * 512 + (ag2 * 16 + am2) * 8 + e0;
        *(uint2*)&hT2[dst] = *(uint2*)v;
    }
}

// ---- Kernel C: occupancy-first fused attention. 32 rows x 1024 j / block ----
// grid (64, 2, 8) = 1024 blocks = 4/CU (LDS 40960 B). 256 thr = 4 waves:
// rr = wv&1 (16-row half), js = wv>>1 (2-word half of each 4-word stage).
// Epilogue combines the js halves IN LDS (r10 bug: both js waves wrote the
// same pacc rows and raced), then stores one partial per (jh).
__global__ __launch_bounds__(256, 4) void attention8(
    const unsigned short* __restrict__ hT2,
    const float* __restrict__ s1L, const float* __restrict__ s2L,
    const unsigned int* __restrict__ bitsT,
    float* __restrict__ pacc, float* __restrict__ pz)
{
    __shared__ __align__(16) unsigned short frag[2][4][4][512];  // 32 KB dbuf
    __shared__ __align__(16) unsigned int mask_lds[2][32][16];   // 4 KB
    __shared__ __align__(16) float s2l[1024];                    // 4 KB

    int t = threadIdx.x, wv = t >> 6, lane = t & 63;
    int am = lane & 15, ag = lane >> 4;
    int rr = wv & 1, js = wv >> 1;
    int bx = blockIdx.x, jh = blockIdx.y, b = blockIdx.z;

    float s1r = s1L[b * Nn + bx * 32 + rr * 16 + am];
    const unsigned short* slab = hT2 + (size_t)b * 131072;

    // stage mask (4 KB) + s2 (4 KB): 1 KB per wave each
    {
        const unsigned int* msrc = bitsT
            + ((size_t)(bx * 2 + (wv >> 1)) * 64 + jh * 32) * 16 + (wv & 1) * 256;
        gll16(msrc + lane * 4, &((unsigned int*)mask_lds)[wv * 256]);
        gll16(s2L + b * Nn + jh * 1024 + wv * 256 + lane * 4, &s2l[wv * 256]);
    }
    // prologue: stage 0 frags (wave wv stages stage-word wv, 4 fb slices)
    {
        const unsigned short* wsrc = slab + ((size_t)(jh * 32 + wv) * 4) * 512;
#pragma unroll
        for (int fb = 0; fb < 4; ++fb)
            gll16(wsrc + fb * 512 + lane * 8, &frag[0][wv][fb][0]);
    }
    asm volatile("s_waitcnt vmcnt(0)" ::: "memory");
    __builtin_amdgcn_s_barrier();

    f32x4 acc0 = {0,0,0,0}, acc1 = {0,0,0,0}, acc2 = {0,0,0,0}, acc3 = {0,0,0,0};
    f32x4 accz = {0,0,0,0};
    const short8 vone = {(short)0x3F80, (short)0x3F80, (short)0x3F80, (short)0x3F80,
                         (short)0x3F80, (short)0x3F80, (short)0x3F80, (short)0x3F80};

#pragma unroll
    for (int st = 0; st < 8; ++st) {
        if (st < 7) {                                   // prefetch next stage
            const unsigned short* wsrc =
                slab + ((size_t)(jh * 32 + (st + 1) * 4 + wv) * 4) * 512;
#pragma unroll
            for (int fb = 0; fb < 4; ++fb)
                gll16(wsrc + fb * 512 + lane * 8, &frag[(st + 1) & 1][wv][fb][0]);
        }
#pragma unroll
        for (int wi = 0; wi < 2; ++wi) {
            int wls = js * 2 + wi;                      // stage-local word
            int wl = st * 4 + wls;                      // block-local word
            unsigned wd = mask_lds[rr][wl][am];
            float4 sa = *(const float4*)&s2l[wl * 32 + 8 * ag];
            float4 sb = *(const float4*)&s2l[wl * 32 + 8 * ag + 4];
            float se[8] = {sa.x, sa.y, sa.z, sa.w, sb.x, sb.y, sb.z, sb.w};
            float p[8];
#pragma unroll
            for (int e = 0; e < 8; ++e) {
                float x = s1r + se[e];
                float lr = fmaxf(x, ALPHA * x);
                float ev = __builtin_amdgcn_exp2f(lr);
                p[e] = ((wd >> (8 * ag + e)) & 1u) ? ev : 0.f;
            }
            int4v aw;
            aw.x = __builtin_amdgcn_perm(__builtin_bit_cast(unsigned, p[1]),
                                         __builtin_bit_cast(unsigned, p[0]), 0x07060302u);
            aw.y = __builtin_amdgcn_perm(__builtin_bit_cast(unsigned, p[3]),
                                         __builtin_bit_cast(unsigned, p[2]), 0x07060302u);
            aw.z = __builtin_amdgcn_perm(__builtin_bit_cast(unsigned, p[5]),
                                         __builtin_bit_cast(unsigned, p[4]), 0x07060302u);
            aw.w = __builtin_amdgcn_perm(__builtin_bit_cast(unsigned, p[7]),
                                         __builtin_bit_cast(unsigned, p[6]), 0x07060302u);
            short8 af = __builtin_bit_cast(short8, aw);
            short8 f0 = *(const short8*)&frag[st & 1][wls][0][lane * 8];
            short8 f1 = *(const short8*)&frag[st & 1][wls][1][lane * 8];
            short8 f2 = *(const short8*)&frag[st & 1][wls][2][lane * 8];
            short8 f3 = *(const short8*)&frag[st & 1][wls][3][lane * 8];
            acc0 = __builtin_amdgcn_mfma_f32_16x16x32_bf16(af, f0, acc0, 0, 0, 0);
            acc1 = __builtin_amdgcn_mfma_f32_16x16x32_bf16(af, f1, acc1, 0, 0, 0);
            acc2 = __builtin_amdgcn_mfma_f32_16x16x32_bf16(af, f2, acc2, 0, 0, 0);
            acc3 = __builtin_amdgcn_mfma_f32_16x16x32_bf16(af, f3, acc3, 0, 0, 0);
            accz = __builtin_amdgcn_mfma_f32_16x16x32_bf16(af, vone, accz, 0, 0, 0);
        }
        asm volatile("s_waitcnt vmcnt(0)" ::: "memory");
        __builtin_amdgcn_s_barrier();
    }

    // ---- epilogue: combine js halves in LDS, store one partial per jh ----
    float* ep  = (float*)&frag[0][0][0][0];      // 16 KB scratch (frag[0] dead)
    float* zep = (float*)&mask_lds[0][0][0];     // 256 B scratch (mask dead)
#pragma unroll
    for (int q = 0; q < 4; ++q) {
        int rloc = rr * 16 + 4 * ag + q;
        ep[(js * 32 + rloc) * 64 +  0 + am] = acc0[q];
        ep[(js * 32 + rloc) * 64 + 16 + am] = acc1[q];
        ep[(js * 32 + rloc) * 64 + 32 + am] = acc2[q];
        ep[(js * 32 + rloc) * 64 + 48 + am] = acc3[q];
        if (am == 0) zep[js * 32 + rloc] = accz[q];
    }
    __syncthreads();

    int rl = t >> 3, fo = (t & 7) * 8;           // 32 rows x 8 f-octets
    float zsum = zep[rl] + zep[32 + rl];
    const float* e0p = &ep[rl * 64 + fo];
    const float* e1p = &ep[(32 + rl) * 64 + fo];
    size_t prow = (size_t)(b * 2 + jh) * 2048 + bx * 32 + rl;
    float4 v0, v1;
    v0.x = e0p[0] + e1p[0]; v0.y = e0p[1] + e1p[1];
    v0.z = e0p[2] + e1p[2]; v0.w = e0p[3] + e1p[3];
    v1.x = e0p[4] + e1p[4]; v1.y = e0p[5] + e1p[5];
    v1.z = e0p[6] + e1p[6]; v1.w = e0p[7] + e1p[7];
    *(float4*)&pacc[prow * 64 + fo]     = v0;
    *(float4*)&pacc[prow * 64 + fo + 4] = v1;
    if ((t & 7) == 0) pz[prow] = zsum;
}

// ---- Kernel D: combine j-halves, normalize, residual, elu ------------------
__global__ __launch_bounds__(256) void combine(
    const float* __restrict__ pacc, const float* __restrict__ pz,
    const float* __restrict__ h, float* __restrict__ out)
{
    int u = blockIdx.x * 256 + threadIdx.x;      // (b*2048+i) * 16 fquads
    int fq = u & 15, grow = u >> 4;
    int b = grow >> 11, i = grow & 2047;
    size_t p0 = ((size_t)(b * 2) * 2048 + i) * 64 + fq * 4;
    float4 a0 = *(const float4*)&pacc[p0];
    float4 a1 = *(const float4*)&pacc[p0 + (size_t)2048 * 64];
    float z = pz[(size_t)(b * 2) * 2048 + i] + pz[(size_t)(b * 2 + 1) * 2048 + i];
    float zinv = 1.f / z;
    size_t ob = (size_t)grow * 64 + fq * 4;
    float4 hv = *(const float4*)&h[ob];
    float4 o;
    o.x = (a0.x + a1.x) * zinv + hv.x; o.x = o.x > 0.f ? o.x : expm1f(o.x);
    o.y = (a0.y + a1.y) * zinv + hv.y; o.y = o.y > 0.f ? o.y : expm1f(o.y);
    o.z = (a0.z + a1.z) * zinv + hv.z; o.z = o.z > 0.f ? o.z : expm1f(o.z);
    o.w = (a0.w + a1.w) * zinv + hv.w; o.w = o.w > 0.f ? o.w : expm1f(o.w);
    *(float4*)&out[ob] = o;
}

// ---------------- launch ----------------
extern "C" void kernel_launch(void* const* d_in, const int* in_sizes, int n_in,
                              void* d_out, int out_size, void* d_ws, size_t ws_size,
                              hipStream_t stream) {
    const float* in  = (const float*)d_in[0];
    const int*   adj = (const int*)d_in[1];
    const float* W   = (const float*)d_in[2];
    const float* a   = (const float*)d_in[3];
    const float* nw  = (const float*)d_in[4];
    const float* nb  = (const float*)d_in[5];
    const float* gam = (const float*)d_in[6];
    const float* bet = (const float*)d_in[7];
    float* out = (float*)d_out;

    char* ws = (char*)d_ws;
    float* h   = (float*)ws;                                       // 4 MB
    float* s1L = (float*)(ws + (size_t)Bb * Nn * 64 * 4);          // 64 KB
    float* s2L = s1L + (size_t)Bb * Nn;                            // 64 KB
    unsigned int* bitsT = (unsigned int*)(s2L + (size_t)Bb * Nn);  // 512 KB
    unsigned short* hT2 = (unsigned short*)(bitsT + (size_t)Nn * Nn / 32); // 2 MB
    float* pacc = (float*)(hT2 + (size_t)Bb * 64 * Nn);            // 8 MB
    float* pz   = pacc + (size_t)16 * 2048 * 64;                   // 128 KB

    hipLaunchKernelGGL(pack_mask, dim3(Nn * Nn / 256), dim3(256), 0, stream, adj, bitsT);
    hipLaunchKernelGGL(node_transform, dim3(Bb * Nn / 4), dim3(256), 0, stream,
                       in, W, a, nw, nb, gam, bet, h, s1L, s2L, hT2);
    hipLaunchKernelGGL(attention8, dim3(Nn / 32, 2, Bb), dim3(256), 0, stream,
                       hT2, s1L, s2L, bitsT, pacc, pz);
    hipLaunchKernelGGL(combine, dim3((Bb * Nn * 16) / 256), dim3(256), 0, stream,
                       pacc, pz, h, out);
}